// Round 3
// baseline (7068.604 us; speedup 1.0000x reference)
//
#include <hip/hip_runtime.h>
#include <hip/hip_bf16.h>

// DeeperGCN on MI355X — round 3: bf16-storage fp32-compute pipeline, CSR aggregation.
// N=150000, E=300000, G=4096, H=256, L=7.
// Workspace ≈ 173 MB: P,T node buffers in bf16 (153.6 MB) + VN fp32 (16.8 MB) + CSR ints (2.4 MB).
// If ws_size < NEED: out[0] = 100000 + ws_MB (diagnostic via absmax).

#define Ncnt 150000
#define Ecnt 300000
#define Gcnt 4096
#define Hc 256
#define Lcnt 7
#define BN_EPS 1e-5f
#define MSG_EPS 1e-7f

typedef __hip_bfloat16 bf16;

static __device__ __forceinline__ int imin(int a, int b) { return a < b ? a : b; }

static __device__ __forceinline__ float ld1(const float* p) { return *p; }
static __device__ __forceinline__ float ld1(const bf16* p) { return __bfloat162float(*p); }
static __device__ __forceinline__ void st1(float* p, float v) { *p = v; }
static __device__ __forceinline__ void st1(bf16* p, float v) { *p = __float2bfloat16(v); }

static __device__ __forceinline__ float4 ld4(const float* p) { return *(const float4*)p; }
static __device__ __forceinline__ float4 ld4(const bf16* p) {
  ushort4 u = *(const ushort4*)p;
  float4 r;
  r.x = __bfloat162float(*(const bf16*)&u.x);
  r.y = __bfloat162float(*(const bf16*)&u.y);
  r.z = __bfloat162float(*(const bf16*)&u.z);
  r.w = __bfloat162float(*(const bf16*)&u.w);
  return r;
}

__global__ __launch_bounds__(256) void k_zero(float* __restrict__ p, int n) {
  int i = blockIdx.x * 256 + threadIdx.x;
  if (i < n) p[i] = 0.f;
}

__global__ __launch_bounds__(256) void k_zero_int(int* __restrict__ p, int n) {
  int i = blockIdx.x * 256 + threadIdx.x;
  if (i < n) p[i] = 0;
}

__global__ __launch_bounds__(256) void k_copy(float* __restrict__ dst, const float* __restrict__ src, int n) {
  int i = blockIdx.x * 256 + threadIdx.x;
  if (i < n) dst[i] = src[i];
}

__global__ void k_diag(float* __restrict__ out, float v) { out[0] = v; }

// ---- CSR build (counting sort by dst) ----
__global__ __launch_bounds__(256) void k_count(const int* __restrict__ ei, int* __restrict__ cnt) {
  int e = blockIdx.x * 256 + threadIdx.x;
  if (e < Ecnt) atomicAdd(&cnt[ei[Ecnt + e]], 1);
}

// single block, 1024 threads: exclusive scan of cnt[N] -> rowptr[N+1]; cursor = start offsets
__global__ __launch_bounds__(1024) void k_scan(const int* __restrict__ cnt, int* __restrict__ rowptr,
                                               int* __restrict__ cursor) {
  __shared__ int part[1024];
  const int chunk = (Ncnt + 1023) / 1024;
  int t = threadIdx.x;
  int lo = t * chunk;
  int hi = imin(lo + chunk, Ncnt);
  if (lo > Ncnt) lo = Ncnt;
  if (hi < lo) hi = lo;
  int s = 0;
  for (int i = lo; i < hi; ++i) s += cnt[i];
  part[t] = s;
  __syncthreads();
  if (t == 0) {
    int run = 0;
    for (int i = 0; i < 1024; ++i) { int tmp = part[i]; part[i] = run; run += tmp; }
  }
  __syncthreads();
  int run = part[t];
  for (int i = lo; i < hi; ++i) {
    int c = cnt[i];
    rowptr[i] = run;
    cursor[i] = run;
    run += c;
  }
  if (hi == Ncnt) rowptr[Ncnt] = run;  // benign multi-write of E
}

__global__ __launch_bounds__(256) void k_scatter(const int* __restrict__ ei, int* __restrict__ cursor,
                                                 int* __restrict__ eidx) {
  int e = blockIdx.x * 256 + threadIdx.x;
  if (e < Ecnt) {
    int d = ei[Ecnt + e];
    int pos = atomicAdd(&cursor[d], 1);
    eidx[pos] = e;
  }
}

// ---- encoders ----
__global__ __launch_bounds__(256) void k_atom_encode(const int* __restrict__ x,
                                                     const float* __restrict__ aemb,
                                                     const float* __restrict__ vnw,
                                                     bf16* __restrict__ P) {
  int c = threadIdx.x;
  int r = blockIdx.x;
  const int* xr = x + (size_t)r * 9;
  float v = vnw[c];
#pragma unroll
  for (int f = 0; f < 9; ++f) v += aemb[(size_t)((f << 6) + xr[f]) * Hc + c];
  st1(&P[(size_t)r * Hc + c], v);
}

__global__ __launch_bounds__(256) void k_init_vn(float* __restrict__ vn, const float* __restrict__ vnw) {
  vn[(size_t)blockIdx.x * Hc + threadIdx.x] = vnw[threadIdx.x];
}

// ---- aggregation: T[r] = h2(r) + sum_{e: dst=r} (relu(h2(src)+bond_emb)+eps)
// h2(n) = P[n] (stats==null, layer 0)  or  relu(bn(P[n]))+vn[batch[n]]
__global__ __launch_bounds__(256) void k_agg(const bf16* __restrict__ P, bf16* __restrict__ T,
                                             const int* __restrict__ rowptr, const int* __restrict__ eidx,
                                             const int* __restrict__ ei, const int* __restrict__ ea,
                                             const float* __restrict__ bemb,
                                             const float* __restrict__ vn, const int* __restrict__ batch,
                                             const float* __restrict__ stats,
                                             const float* __restrict__ gamma, const float* __restrict__ beta,
                                             float invM) {
  int c = threadIdx.x;
  int r = blockIdx.x;
  float sc = 0.f, bb = 0.f;
  if (stats) {
    float mu = stats[c] * invM;
    float var = stats[Hc + c] * invM - mu * mu;
    sc = rsqrtf(var + BN_EPS) * gamma[c];
    bb = beta[c] - mu * sc;
  }
  float acc;
  {
    float v = ld1(&P[(size_t)r * Hc + c]);
    if (stats) v = fmaxf(fmaf(v, sc, bb), 0.f) + vn[(size_t)batch[r] * Hc + c];
    acc = v;
  }
  int j1 = rowptr[r + 1];
  for (int j = rowptr[r]; j < j1; ++j) {
    int e = eidx[j];
    int s = ei[e];
    int a0 = ea[e * 3], a1 = ea[e * 3 + 1], a2 = ea[e * 3 + 2];
    float em = bemb[(size_t)a0 * Hc + c] + bemb[(size_t)(8 + a1) * Hc + c] + bemb[(size_t)(16 + a2) * Hc + c];
    float v = ld1(&P[(size_t)s * Hc + c]);
    if (stats) v = fmaxf(fmaf(v, sc, bb), 0.f) + vn[(size_t)batch[s] * Hc + c];
    acc += fmaxf(v + em, 0.f) + MSG_EPS;
  }
  st1(&T[(size_t)r * Hc + c], acc);
}

// ---- BN stats: per-channel sum/sumsq over M rows (stats pre-zeroed) ----
template <typename TH>
__global__ __launch_bounds__(256) void k_bn_stats(const TH* __restrict__ h, float* __restrict__ stats, int M) {
  int c = threadIdx.x;
  int r0 = blockIdx.x * 256;
  if (r0 >= M) return;
  int r1 = imin(r0 + 256, M);
  float s = 0.f, q = 0.f;
  for (int r = r0; r < r1; ++r) {
    float v = ld1(&h[(size_t)r * Hc + c]);
    s += v;
    q = fmaf(v, v, q);
  }
  atomicAdd(&stats[c], s);
  atomicAdd(&stats[Hc + c], q);
}

// segment-sum of relu(bn(P)) by sorted batch into vnt (pre-initialized with vn)
__global__ __launch_bounds__(256) void k_seg_vn(const bf16* __restrict__ P, const int* __restrict__ batch,
                                                float* __restrict__ vnt, const float* __restrict__ stats,
                                                const float* __restrict__ gamma, const float* __restrict__ beta,
                                                int M, float invM) {
  int c = threadIdx.x;
  float mu = stats[c] * invM;
  float var = stats[Hc + c] * invM - mu * mu;
  float sc = rsqrtf(var + BN_EPS) * gamma[c];
  float bb = beta[c] - mu * sc;
  int r0 = blockIdx.x * 64;
  if (r0 >= M) return;
  int r1 = imin(r0 + 64, M);
  float acc = 0.f;
  int curg = batch[r0];
  for (int r = r0; r < r1; ++r) {
    int g = batch[r];
    float v = fmaxf(fmaf(ld1(&P[(size_t)r * Hc + c]), sc, bb), 0.f);
    if (g != curg) {
      atomicAdd(&vnt[(size_t)curg * Hc + c], acc);
      acc = 0.f;
      curg = g;
    }
    acc += v;
  }
  atomicAdd(&vnt[(size_t)curg * Hc + c], acc);
}

__global__ __launch_bounds__(256) void k_bn_relu_vec(const float* __restrict__ in, float* __restrict__ out,
                                                     const float* __restrict__ stats,
                                                     const float* __restrict__ gamma, const float* __restrict__ beta,
                                                     float invM) {
  int c = threadIdx.x;
  int r = blockIdx.x;
  float mu = stats[c] * invM;
  float var = stats[Hc + c] * invM - mu * mu;
  float sc = rsqrtf(var + BN_EPS) * gamma[c];
  float bb = beta[c] - mu * sc;
  out[(size_t)r * Hc + c] = fmaxf(fmaf(in[(size_t)r * Hc + c], sc, bb), 0.f);
}

// final bn + global_add_pool into out [G,H] (out pre-zeroed)
__global__ __launch_bounds__(256) void k_bn_pool(const bf16* __restrict__ h, const int* __restrict__ batch,
                                                 float* __restrict__ out, const float* __restrict__ stats,
                                                 const float* __restrict__ gamma, const float* __restrict__ beta,
                                                 int M, float invM) {
  int c = threadIdx.x;
  float mu = stats[c] * invM;
  float var = stats[Hc + c] * invM - mu * mu;
  float sc = rsqrtf(var + BN_EPS) * gamma[c];
  float bb = beta[c] - mu * sc;
  int r0 = blockIdx.x * 64;
  if (r0 >= M) return;
  int r1 = imin(r0 + 64, M);
  float acc = 0.f;
  int curg = batch[r0];
  for (int r = r0; r < r1; ++r) {
    int g = batch[r];
    float v = fmaf(ld1(&h[(size_t)r * Hc + c]), sc, bb);
    if (g != curg) {
      atomicAdd(&out[(size_t)curg * Hc + c], acc);
      acc = 0.f;
      curg = g;
    }
    acc += v;
  }
  atomicAdd(&out[(size_t)curg * Hc + c], acc);
}

// C[M,256] = A[M,256] @ W[256,256] + bias (+ R). 64x64 tile, fp32 compute.
template <typename TA, typename TR>
__global__ __launch_bounds__(256) void k_gemm(const TA* __restrict__ A, const float* __restrict__ W,
                                              const float* __restrict__ bias, const TR* __restrict__ R,
                                              TR* __restrict__ C, int M) {
  __shared__ float As[64][68];
  __shared__ float Ws[64][68];
  int tid = threadIdx.x;
  int row0 = blockIdx.x * 64;
  int col0 = blockIdx.y * 64;
  int tx = tid & 15, ty = tid >> 4;
  float acc[4][4] = {{0.f}};
  for (int k0 = 0; k0 < 256; k0 += 64) {
#pragma unroll
    for (int i = 0; i < 4; ++i) {
      int lin = tid + i * 256;  // 1024 4-elem slots = 64 rows x 16 cols
      int r = lin >> 4;
      int c4 = (lin & 15) << 2;
      int gr = row0 + r;
      float4 v = make_float4(0.f, 0.f, 0.f, 0.f);
      if (gr < M) v = ld4(&A[(size_t)gr * Hc + k0 + c4]);
      As[r][c4] = v.x; As[r][c4 + 1] = v.y; As[r][c4 + 2] = v.z; As[r][c4 + 3] = v.w;
      float4 w = ld4(&W[(size_t)(k0 + r) * Hc + col0 + c4]);
      Ws[r][c4] = w.x; Ws[r][c4 + 1] = w.y; Ws[r][c4 + 2] = w.z; Ws[r][c4 + 3] = w.w;
    }
    __syncthreads();
#pragma unroll
    for (int k = 0; k < 64; ++k) {
      float a[4], w[4];
#pragma unroll
      for (int i = 0; i < 4; ++i) a[i] = As[ty * 4 + i][k];
#pragma unroll
      for (int j = 0; j < 4; ++j) w[j] = Ws[k][tx * 4 + j];
#pragma unroll
      for (int i = 0; i < 4; ++i)
#pragma unroll
        for (int j = 0; j < 4; ++j) acc[i][j] = fmaf(a[i], w[j], acc[i][j]);
    }
    __syncthreads();
  }
#pragma unroll
  for (int i = 0; i < 4; ++i) {
    int gr = row0 + ty * 4 + i;
    if (gr >= M) break;
#pragma unroll
    for (int j = 0; j < 4; ++j) {
      int gc = col0 + tx * 4 + j;
      float v = acc[i][j] + bias[gc];
      if (R) v += ld1(&R[(size_t)gr * Hc + gc]);
      st1(&C[(size_t)gr * Hc + gc], v);
    }
  }
}

extern "C" void kernel_launch(void* const* d_in, const int* in_sizes, int n_in,
                              void* d_out, int out_size, void* d_ws, size_t ws_size,
                              hipStream_t stream) {
  const int* x = (const int*)d_in[0];
  const int* ei = (const int*)d_in[1];
  const int* ea = (const int*)d_in[2];
  const int* batch = (const int*)d_in[3];
  const float* aemb = (const float*)d_in[4];
  const float* bemb = (const float*)d_in[5];
  const float* vnw = (const float*)d_in[6];
  const float* conv_w = (const float*)d_in[7];
  const float* conv_b = (const float*)d_in[8];
  const float* ngamma = (const float*)d_in[9];
  const float* nbeta = (const float*)d_in[10];
  const float* vn_w = (const float*)d_in[11];
  const float* vn_b = (const float*)d_in[12];
  const float* vn_g = (const float*)d_in[13];
  const float* vn_be = (const float*)d_in[14];
  float* out = (float*)d_out;

  const size_t NODE = (size_t)Ncnt * Hc;  // 38.4M elems
  const size_t GH = (size_t)Gcnt * Hc;    // 1.05M elems
  const size_t NEED = (4 * GH + 4 * Hc) * sizeof(float)           // vn,vnt,vnu,vnv,stats
                      + (size_t)(2 * Ncnt + 1 + Ecnt) * sizeof(int)  // rowptr,cursor,eidx
                      + 2 * NODE * sizeof(bf16);                  // P,T
  if (ws_size < NEED) {
    // diagnostic: absmax ≈ 100000 + ws_MB
    k_zero<<<(int)((GH + 255) / 256), 256, 0, stream>>>(out, (int)GH);
    k_diag<<<1, 1, 0, stream>>>(out, 100000.f + (float)(ws_size / (1024.0 * 1024.0)));
    return;
  }

  float* fp = (float*)d_ws;
  float* vn = fp;
  float* vnt = vn + GH;
  float* vnu = vnt + GH;
  float* vnv = vnu + GH;
  float* statsN = vnv + GH;
  float* statsV = statsN + 2 * Hc;
  int* rowptr = (int*)(statsV + 2 * Hc);
  int* cursor = rowptr + (Ncnt + 1);
  int* eidx = cursor + Ncnt;
  bf16* P = (bf16*)(eidx + Ecnt);
  bf16* T = P + NODE;

  const int nBlk256 = (Ncnt + 255) / 256;  // 586
  const int nBlk64 = (Ncnt + 63) / 64;     // 2344
  const int gBlk256 = (Gcnt + 255) / 256;  // 16
  const int eBlk = (Ecnt + 255) / 256;     // 1172
  const dim3 gg((Ncnt + 63) / 64, 4);
  const dim3 gv((Gcnt + 63) / 64, 4);
  const float invN = 1.f / Ncnt;
  const float invG = 1.f / Gcnt;

  // CSR build
  k_zero_int<<<(Ncnt + 255) / 256, 256, 0, stream>>>(cursor, Ncnt);
  k_count<<<eBlk, 256, 0, stream>>>(ei, cursor);
  k_scan<<<1, 1024, 0, stream>>>(cursor, rowptr, cursor);
  k_scatter<<<eBlk, 256, 0, stream>>>(ei, cursor, eidx);

  // Encoders + conv0
  k_atom_encode<<<Ncnt, 256, 0, stream>>>(x, aemb, vnw, P);
  k_init_vn<<<Gcnt, 256, 0, stream>>>(vn, vnw);
  k_agg<<<Ncnt, 256, 0, stream>>>(P, T, rowptr, eidx, ei, ea, bemb,
                                  nullptr, nullptr, nullptr, nullptr, nullptr, 0.f);
  k_gemm<bf16, bf16><<<gg, 256, 0, stream>>>(T, conv_w, conv_b, nullptr, P, Ncnt);

  for (int l = 1; l < Lcnt; ++l) {
    int p = l - 1;
    const float* g = ngamma + (size_t)p * Hc;
    const float* b = nbeta + (size_t)p * Hc;
    // node BN stats
    k_zero<<<2, 256, 0, stream>>>(statsN, 2 * Hc);
    k_bn_stats<bf16><<<nBlk256, 256, 0, stream>>>(P, statsN, Ncnt);
    // vn_t = vn + segsum(relu(bn(P)))
    k_copy<<<(int)(GH / 256), 256, 0, stream>>>(vnt, vn, (int)GH);
    k_seg_vn<<<nBlk64, 256, 0, stream>>>(P, batch, vnt, statsN, g, b, Ncnt, invN);
    // VN MLP j=0
    k_gemm<float, float><<<gv, 256, 0, stream>>>(vnt, vn_w + ((size_t)p * 2 + 0) * Hc * Hc,
                                                 vn_b + ((size_t)p * 2 + 0) * Hc, nullptr, vnu, Gcnt);
    k_zero<<<2, 256, 0, stream>>>(statsV, 2 * Hc);
    k_bn_stats<float><<<gBlk256, 256, 0, stream>>>(vnu, statsV, Gcnt);
    k_bn_relu_vec<<<Gcnt, 256, 0, stream>>>(vnu, vnv, statsV,
                                            vn_g + ((size_t)p * 2 + 0) * Hc,
                                            vn_be + ((size_t)p * 2 + 0) * Hc, invG);
    // VN MLP j=1 -> vn
    k_gemm<float, float><<<gv, 256, 0, stream>>>(vnv, vn_w + ((size_t)p * 2 + 1) * Hc * Hc,
                                                 vn_b + ((size_t)p * 2 + 1) * Hc, nullptr, vnu, Gcnt);
    k_zero<<<2, 256, 0, stream>>>(statsV, 2 * Hc);
    k_bn_stats<float><<<gBlk256, 256, 0, stream>>>(vnu, statsV, Gcnt);
    k_bn_relu_vec<<<Gcnt, 256, 0, stream>>>(vnu, vn, statsV,
                                            vn_g + ((size_t)p * 2 + 1) * Hc,
                                            vn_be + ((size_t)p * 2 + 1) * Hc, invG);
    // T = h2 + agg(h2) with h2 = relu(bn(P)) + vn[batch]
    k_agg<<<Ncnt, 256, 0, stream>>>(P, T, rowptr, eidx, ei, ea, bemb, vn, batch, statsN, g, b, invN);
    // P = T @ W + bias + P
    k_gemm<bf16, bf16><<<gg, 256, 0, stream>>>(T, conv_w + (size_t)l * Hc * Hc,
                                               conv_b + (size_t)l * Hc, P, P, Ncnt);
  }

  // Final BN + global add pool
  k_zero<<<2, 256, 0, stream>>>(statsN, 2 * Hc);
  k_bn_stats<bf16><<<nBlk256, 256, 0, stream>>>(P, statsN, Ncnt);
  k_zero<<<(int)((GH + 255) / 256), 256, 0, stream>>>(out, (int)GH);
  k_bn_pool<<<nBlk64, 256, 0, stream>>>(P, batch, out, statsN,
                                        ngamma + (size_t)(Lcnt - 1) * Hc, nbeta + (size_t)(Lcnt - 1) * Hc,
                                        Ncnt, invN);
}

// Round 5
// 4313.728 us; speedup vs baseline: 1.6386x; 1.6386x over previous
//
#include <hip/hip_runtime.h>
#include <hip/hip_bf16.h>

// DeeperGCN on MI355X — round 5: MFMA bf16 node GEMM (W hi/lo) + fused node BN-stats;
// VN stream reverted to full fp32 (coherent bf16 error on vn was amplified ~37x by pooling).
// N=150000, E=300000, G=4096, H=256, L=7.

#define Ncnt 150000
#define Ecnt 300000
#define Gcnt 4096
#define Hc 256
#define Lcnt 7
#define BN_EPS 1e-5f
#define MSG_EPS 1e-7f

typedef __hip_bfloat16 bf16;
typedef __attribute__((ext_vector_type(8))) short bf16x8;
typedef __attribute__((ext_vector_type(4))) float f32x4;

static __device__ __forceinline__ int imin(int a, int b) { return a < b ? a : b; }

static __device__ __forceinline__ float bs2f(unsigned short s) {
  unsigned u = ((unsigned)s) << 16;
  union { unsigned u; float f; } c; c.u = u; return c.f;
}
static __device__ __forceinline__ unsigned short f2bs(float f) {
  bf16 h = __float2bfloat16(f);
  union { bf16 h; unsigned short s; } c; c.h = h; return c.s;
}
static __device__ __forceinline__ float4 bf4tof4(ushort4 u) {
  float4 r; r.x = bs2f(u.x); r.y = bs2f(u.y); r.z = bs2f(u.z); r.w = bs2f(u.w); return r;
}
static __device__ __forceinline__ ushort4 f4tobf4(float4 v) {
  ushort4 u; u.x = f2bs(v.x); u.y = f2bs(v.y); u.z = f2bs(v.z); u.w = f2bs(v.w); return u;
}

__global__ __launch_bounds__(256) void k_zero(float* __restrict__ p, int n) {
  int i = blockIdx.x * 256 + threadIdx.x;
  if (i < n) p[i] = 0.f;
}
__global__ __launch_bounds__(256) void k_zero_int(int* __restrict__ p, int n) {
  int i = blockIdx.x * 256 + threadIdx.x;
  if (i < n) p[i] = 0;
}
__global__ __launch_bounds__(256) void k_copy(float* __restrict__ dst, const float* __restrict__ src, int n) {
  int i = blockIdx.x * 256 + threadIdx.x;
  if (i < n) dst[i] = src[i];
}
__global__ void k_diag(float* __restrict__ out, float v) { out[0] = v; }

// ---- CSR build (counting sort by dst) ----
__global__ __launch_bounds__(256) void k_count(const int* __restrict__ ei, int* __restrict__ cnt) {
  int e = blockIdx.x * 256 + threadIdx.x;
  if (e < Ecnt) atomicAdd(&cnt[ei[Ecnt + e]], 1);
}
__global__ __launch_bounds__(1024) void k_scan(const int* __restrict__ cnt, int* __restrict__ rowptr,
                                               int* __restrict__ cursor) {
  __shared__ int part[1024];
  const int chunk = (Ncnt + 1023) / 1024;
  int t = threadIdx.x;
  int lo = t * chunk;
  int hi = imin(lo + chunk, Ncnt);
  if (lo > Ncnt) lo = Ncnt;
  if (hi < lo) hi = lo;
  int s = 0;
  for (int i = lo; i < hi; ++i) s += cnt[i];
  part[t] = s;
  __syncthreads();
  if (t == 0) {
    int run = 0;
    for (int i = 0; i < 1024; ++i) { int tmp = part[i]; part[i] = run; run += tmp; }
  }
  __syncthreads();
  int run = part[t];
  for (int i = lo; i < hi; ++i) {
    int c = cnt[i];
    rowptr[i] = run;
    cursor[i] = run;
    run += c;
  }
  if (hi == Ncnt) rowptr[Ncnt] = run;
}
__global__ __launch_bounds__(256) void k_scatter(const int* __restrict__ ei, int* __restrict__ cursor,
                                                 int* __restrict__ eidx) {
  int e = blockIdx.x * 256 + threadIdx.x;
  if (e < Ecnt) {
    int d = ei[Ecnt + e];
    int pos = atomicAdd(&cursor[d], 1);
    eidx[pos] = e;
  }
}

// ---- weight prep: conv W[k][n] fp32 -> transposed bf16 hi/lo Wt[n][k] ----
__global__ __launch_bounds__(256) void k_prep_w(const float* __restrict__ W, bf16* __restrict__ hi,
                                                bf16* __restrict__ lo, int nmats) {
  int idx = blockIdx.x * 256 + threadIdx.x;
  if (idx >= nmats * 65536) return;
  int m = idx >> 16;
  int r = idx & 65535;
  int n = r >> 8, k = r & 255;
  float w = W[(size_t)m * 65536 + (size_t)k * 256 + n];
  bf16 h = __float2bfloat16(w);
  float res = w - __bfloat162float(h);
  hi[idx] = h;
  lo[idx] = __float2bfloat16(res);
}

// ---- encoders (1 wave per node, 4 ch/lane) ----
__global__ __launch_bounds__(256) void k_atom_encode(const int* __restrict__ x,
                                                     const float* __restrict__ aemb,
                                                     const float* __restrict__ vnw,
                                                     bf16* __restrict__ P) {
  int wave = threadIdx.x >> 6, lane = threadIdx.x & 63;
  int r = blockIdx.x * 4 + wave;
  if (r >= Ncnt) return;
  int c4 = lane * 4;
  const int* xr = x + (size_t)r * 9;
  float4 v = *(const float4*)&vnw[c4];
#pragma unroll
  for (int f = 0; f < 9; ++f) {
    float4 e = *(const float4*)&aemb[(size_t)((f << 6) + xr[f]) * Hc + c4];
    v.x += e.x; v.y += e.y; v.z += e.z; v.w += e.w;
  }
  *(ushort4*)&P[(size_t)r * Hc + c4] = f4tobf4(v);
}

__global__ __launch_bounds__(256) void k_init_vn(float* __restrict__ vn, const float* __restrict__ vnw) {
  int idx = blockIdx.x * 256 + threadIdx.x;  // G*Hc total
  vn[idx] = vnw[idx & (Hc - 1)];
}

// ---- aggregation: T[r] = h2(r) + sum_{e: dst=r} (relu(h2(src)+bond_emb)+eps)
// h2(n) = P[n] (stats==null) or relu(bn(P[n]))+vn[batch[n]].  1 wave/node.
__global__ __launch_bounds__(256) void k_agg(const bf16* __restrict__ P, bf16* __restrict__ T,
                                             const int* __restrict__ rowptr, const int* __restrict__ eidx,
                                             const int* __restrict__ ei, const int* __restrict__ ea,
                                             const float* __restrict__ bemb,
                                             const float* __restrict__ vn, const int* __restrict__ batch,
                                             const float* __restrict__ stats,
                                             const float* __restrict__ gamma, const float* __restrict__ beta,
                                             float invM) {
  int wave = threadIdx.x >> 6, lane = threadIdx.x & 63;
  int r = blockIdx.x * 4 + wave;
  if (r >= Ncnt) return;
  int c4 = lane * 4;
  bool hasbn = (stats != nullptr);
  float4 scv = make_float4(1.f, 1.f, 1.f, 1.f), bbv = make_float4(0.f, 0.f, 0.f, 0.f);
  if (hasbn) {
    float4 sv = *(const float4*)&stats[c4];
    float4 qv = *(const float4*)&stats[Hc + c4];
    float4 gv = *(const float4*)&gamma[c4];
    float4 bv = *(const float4*)&beta[c4];
    float mu, var;
    mu = sv.x * invM; var = qv.x * invM - mu * mu; scv.x = rsqrtf(var + BN_EPS) * gv.x; bbv.x = bv.x - mu * scv.x;
    mu = sv.y * invM; var = qv.y * invM - mu * mu; scv.y = rsqrtf(var + BN_EPS) * gv.y; bbv.y = bv.y - mu * scv.y;
    mu = sv.z * invM; var = qv.z * invM - mu * mu; scv.z = rsqrtf(var + BN_EPS) * gv.z; bbv.z = bv.z - mu * scv.z;
    mu = sv.w * invM; var = qv.w * invM - mu * mu; scv.w = rsqrtf(var + BN_EPS) * gv.w; bbv.w = bv.w - mu * scv.w;
  }
  float4 acc;
  {
    float4 v = bf4tof4(*(const ushort4*)&P[(size_t)r * Hc + c4]);
    if (hasbn) {
      v.x = fmaxf(fmaf(v.x, scv.x, bbv.x), 0.f); v.y = fmaxf(fmaf(v.y, scv.y, bbv.y), 0.f);
      v.z = fmaxf(fmaf(v.z, scv.z, bbv.z), 0.f); v.w = fmaxf(fmaf(v.w, scv.w, bbv.w), 0.f);
      const float4 w = *(const float4*)&vn[(size_t)batch[r] * Hc + c4];
      v.x += w.x; v.y += w.y; v.z += w.z; v.w += w.w;
    }
    acc = v;
  }
  int j1 = rowptr[r + 1];
  for (int j = rowptr[r]; j < j1; ++j) {
    int e = eidx[j];
    int s = ei[e];
    int a0 = ea[e * 3], a1 = ea[e * 3 + 1], a2 = ea[e * 3 + 2];
    float4 em = *(const float4*)&bemb[(size_t)a0 * Hc + c4];
    float4 e1 = *(const float4*)&bemb[(size_t)(8 + a1) * Hc + c4];
    float4 e2 = *(const float4*)&bemb[(size_t)(16 + a2) * Hc + c4];
    em.x += e1.x + e2.x; em.y += e1.y + e2.y; em.z += e1.z + e2.z; em.w += e1.w + e2.w;
    float4 v = bf4tof4(*(const ushort4*)&P[(size_t)s * Hc + c4]);
    if (hasbn) {
      v.x = fmaxf(fmaf(v.x, scv.x, bbv.x), 0.f); v.y = fmaxf(fmaf(v.y, scv.y, bbv.y), 0.f);
      v.z = fmaxf(fmaf(v.z, scv.z, bbv.z), 0.f); v.w = fmaxf(fmaf(v.w, scv.w, bbv.w), 0.f);
      const float4 w = *(const float4*)&vn[(size_t)batch[s] * Hc + c4];
      v.x += w.x; v.y += w.y; v.z += w.z; v.w += w.w;
    }
    acc.x += fmaxf(v.x + em.x, 0.f) + MSG_EPS;
    acc.y += fmaxf(v.y + em.y, 0.f) + MSG_EPS;
    acc.z += fmaxf(v.z + em.z, 0.f) + MSG_EPS;
    acc.w += fmaxf(v.w + em.w, 0.f) + MSG_EPS;
  }
  *(ushort4*)&T[(size_t)r * Hc + c4] = f4tobf4(acc);
}

// ---- segment-sum of relu(bn(P)) by sorted batch into vnt (pre-init with vn). 1 wave / 64 rows.
__global__ __launch_bounds__(256) void k_seg_vn(const bf16* __restrict__ P, const int* __restrict__ batch,
                                                float* __restrict__ vnt, const float* __restrict__ stats,
                                                const float* __restrict__ gamma, const float* __restrict__ beta,
                                                float invM) {
  int wave = threadIdx.x >> 6, lane = threadIdx.x & 63;
  int base = (blockIdx.x * 4 + wave) * 64;
  if (base >= Ncnt) return;
  int c4 = lane * 4;
  float4 sv = *(const float4*)&stats[c4];
  float4 qv = *(const float4*)&stats[Hc + c4];
  float4 gv = *(const float4*)&gamma[c4];
  float4 bv = *(const float4*)&beta[c4];
  float4 scv, bbv;
  float mu, var;
  mu = sv.x * invM; var = qv.x * invM - mu * mu; scv.x = rsqrtf(var + BN_EPS) * gv.x; bbv.x = bv.x - mu * scv.x;
  mu = sv.y * invM; var = qv.y * invM - mu * mu; scv.y = rsqrtf(var + BN_EPS) * gv.y; bbv.y = bv.y - mu * scv.y;
  mu = sv.z * invM; var = qv.z * invM - mu * mu; scv.z = rsqrtf(var + BN_EPS) * gv.z; bbv.z = bv.z - mu * scv.z;
  mu = sv.w * invM; var = qv.w * invM - mu * mu; scv.w = rsqrtf(var + BN_EPS) * gv.w; bbv.w = bv.w - mu * scv.w;
  int end = imin(base + 64, Ncnt);
  float4 acc = make_float4(0.f, 0.f, 0.f, 0.f);
  int curg = batch[base];
  for (int r = base; r < end; ++r) {
    int g = batch[r];
    float4 v = bf4tof4(*(const ushort4*)&P[(size_t)r * Hc + c4]);
    v.x = fmaxf(fmaf(v.x, scv.x, bbv.x), 0.f); v.y = fmaxf(fmaf(v.y, scv.y, bbv.y), 0.f);
    v.z = fmaxf(fmaf(v.z, scv.z, bbv.z), 0.f); v.w = fmaxf(fmaf(v.w, scv.w, bbv.w), 0.f);
    if (g != curg) {
      float* d = &vnt[(size_t)curg * Hc + c4];
      atomicAdd(d, acc.x); atomicAdd(d + 1, acc.y); atomicAdd(d + 2, acc.z); atomicAdd(d + 3, acc.w);
      acc = make_float4(0.f, 0.f, 0.f, 0.f);
      curg = g;
    }
    acc.x += v.x; acc.y += v.y; acc.z += v.z; acc.w += v.w;
  }
  float* d = &vnt[(size_t)curg * Hc + c4];
  atomicAdd(d, acc.x); atomicAdd(d + 1, acc.y); atomicAdd(d + 2, acc.z); atomicAdd(d + 3, acc.w);
}

// ---- BN stats over fp32 rows (VN path; stats pre-zeroed) ----
__global__ __launch_bounds__(256) void k_bn_stats_f(const float* __restrict__ h, float* __restrict__ stats, int M) {
  int c = threadIdx.x;
  int r0 = blockIdx.x * 256;
  if (r0 >= M) return;
  int r1 = imin(r0 + 256, M);
  float s = 0.f, q = 0.f;
  for (int r = r0; r < r1; ++r) {
    float v = h[(size_t)r * Hc + c];
    s += v;
    q = fmaf(v, v, q);
  }
  atomicAdd(&stats[c], s);
  atomicAdd(&stats[Hc + c], q);
}

// ---- VN elementwise relu(bn(.)) fp32->fp32 ----
__global__ __launch_bounds__(256) void k_vn_relu(const float* __restrict__ in, float* __restrict__ out,
                                                 const float* __restrict__ stats,
                                                 const float* __restrict__ gamma, const float* __restrict__ beta,
                                                 float invM) {
  int idx = blockIdx.x * 256 + threadIdx.x;
  int c = idx & (Hc - 1);
  float mu = stats[c] * invM;
  float var = stats[Hc + c] * invM - mu * mu;
  float sc = rsqrtf(var + BN_EPS) * gamma[c];
  float bb = beta[c] - mu * sc;
  out[idx] = fmaxf(fmaf(in[idx], sc, bb), 0.f);
}

// ---- final bn + global_add_pool (out pre-zeroed). 1 wave / 64 rows.
__global__ __launch_bounds__(256) void k_bn_pool(const bf16* __restrict__ P, const int* __restrict__ batch,
                                                 float* __restrict__ out, const float* __restrict__ stats,
                                                 const float* __restrict__ gamma, const float* __restrict__ beta,
                                                 float invM) {
  int wave = threadIdx.x >> 6, lane = threadIdx.x & 63;
  int base = (blockIdx.x * 4 + wave) * 64;
  if (base >= Ncnt) return;
  int c4 = lane * 4;
  float4 sv = *(const float4*)&stats[c4];
  float4 qv = *(const float4*)&stats[Hc + c4];
  float4 gv = *(const float4*)&gamma[c4];
  float4 bv = *(const float4*)&beta[c4];
  float4 scv, bbv;
  float mu, var;
  mu = sv.x * invM; var = qv.x * invM - mu * mu; scv.x = rsqrtf(var + BN_EPS) * gv.x; bbv.x = bv.x - mu * scv.x;
  mu = sv.y * invM; var = qv.y * invM - mu * mu; scv.y = rsqrtf(var + BN_EPS) * gv.y; bbv.y = bv.y - mu * scv.y;
  mu = sv.z * invM; var = qv.z * invM - mu * mu; scv.z = rsqrtf(var + BN_EPS) * gv.z; bbv.z = bv.z - mu * scv.z;
  mu = sv.w * invM; var = qv.w * invM - mu * mu; scv.w = rsqrtf(var + BN_EPS) * gv.w; bbv.w = bv.w - mu * scv.w;
  int end = imin(base + 64, Ncnt);
  float4 acc = make_float4(0.f, 0.f, 0.f, 0.f);
  int curg = batch[base];
  for (int r = base; r < end; ++r) {
    int g = batch[r];
    float4 v = bf4tof4(*(const ushort4*)&P[(size_t)r * Hc + c4]);
    v.x = fmaf(v.x, scv.x, bbv.x); v.y = fmaf(v.y, scv.y, bbv.y);
    v.z = fmaf(v.z, scv.z, bbv.z); v.w = fmaf(v.w, scv.w, bbv.w);
    if (g != curg) {
      float* d = &out[(size_t)curg * Hc + c4];
      atomicAdd(d, acc.x); atomicAdd(d + 1, acc.y); atomicAdd(d + 2, acc.z); atomicAdd(d + 3, acc.w);
      acc = make_float4(0.f, 0.f, 0.f, 0.f);
      curg = g;
    }
    acc.x += v.x; acc.y += v.y; acc.z += v.z; acc.w += v.w;
  }
  float* d = &out[(size_t)curg * Hc + c4];
  atomicAdd(d, acc.x); atomicAdd(d + 1, acc.y); atomicAdd(d + 2, acc.z); atomicAdd(d + 3, acc.w);
}

// ---- MFMA node GEMM: C[M,256] = A @ (Whi+Wlo) + bias (+R), bf16 in/out, fused BN-stats.
// Wt layout: [n][k] bf16 (pre-transposed). Tile 128x128, BK=64, 4 waves.
__global__ __launch_bounds__(256) void k_gemm_mfma(const bf16* __restrict__ A, const bf16* __restrict__ Whi,
                                                   const bf16* __restrict__ Wlo, const float* __restrict__ bias,
                                                   const bf16* __restrict__ R, bf16* __restrict__ C,
                                                   float* __restrict__ stats, int M) {
  __shared__ short As[128][72];
  __shared__ short Bh[128][72];
  __shared__ short Bl[128][72];
  int tid = threadIdx.x;
  int row0 = blockIdx.x * 128;
  int n0 = blockIdx.y * 128;
  int wave = tid >> 6, lane = tid & 63;
  int quad = lane >> 4, l15 = lane & 15;
  int wr = (wave & 1) * 64, wc = (wave >> 1) * 64;
  f32x4 acc[4][4];
#pragma unroll
  for (int i = 0; i < 4; ++i)
#pragma unroll
    for (int j = 0; j < 4; ++j) acc[i][j] = (f32x4){0.f, 0.f, 0.f, 0.f};

  for (int kc = 0; kc < 256; kc += 64) {
#pragma unroll
    for (int i = 0; i < 4; ++i) {
      int slot = tid + i * 256;
      int r = slot >> 3, seg = (slot & 7) * 8;
      bf16x8 av;
      if (row0 + r < M) av = *(const bf16x8*)&A[(size_t)(row0 + r) * Hc + kc + seg];
      else av = (bf16x8){0, 0, 0, 0, 0, 0, 0, 0};
      *(bf16x8*)&As[r][seg] = av;
      *(bf16x8*)&Bh[r][seg] = *(const bf16x8*)&Whi[(size_t)(n0 + r) * Hc + kc + seg];
      *(bf16x8*)&Bl[r][seg] = *(const bf16x8*)&Wlo[(size_t)(n0 + r) * Hc + kc + seg];
    }
    __syncthreads();
#pragma unroll
    for (int ks = 0; ks < 2; ++ks) {
      int kk = ks * 32 + quad * 8;
      bf16x8 af[4], bh[4], bl[4];
#pragma unroll
      for (int mi = 0; mi < 4; ++mi) af[mi] = *(const bf16x8*)&As[wr + mi * 16 + l15][kk];
#pragma unroll
      for (int ni = 0; ni < 4; ++ni) {
        bh[ni] = *(const bf16x8*)&Bh[wc + ni * 16 + l15][kk];
        bl[ni] = *(const bf16x8*)&Bl[wc + ni * 16 + l15][kk];
      }
#pragma unroll
      for (int mi = 0; mi < 4; ++mi)
#pragma unroll
        for (int ni = 0; ni < 4; ++ni)
          acc[mi][ni] = __builtin_amdgcn_mfma_f32_16x16x32_bf16(af[mi], bh[ni], acc[mi][ni], 0, 0, 0);
#pragma unroll
      for (int mi = 0; mi < 4; ++mi)
#pragma unroll
        for (int ni = 0; ni < 4; ++ni)
          acc[mi][ni] = __builtin_amdgcn_mfma_f32_16x16x32_bf16(af[mi], bl[ni], acc[mi][ni], 0, 0, 0);
    }
    __syncthreads();
  }

  float ssum[4] = {0.f, 0.f, 0.f, 0.f}, ssq[4] = {0.f, 0.f, 0.f, 0.f};
#pragma unroll
  for (int ni = 0; ni < 4; ++ni) {
    int col = n0 + wc + ni * 16 + l15;
    float bcol = bias[col];
#pragma unroll
    for (int mi = 0; mi < 4; ++mi) {
#pragma unroll
      for (int j = 0; j < 4; ++j) {
        int row = row0 + wr + mi * 16 + quad * 4 + j;
        if (row < M) {
          float v = acc[mi][ni][j] + bcol;
          if (R) v += __bfloat162float(R[(size_t)row * Hc + col]);
          C[(size_t)row * Hc + col] = __float2bfloat16(v);
          ssum[ni] += v;
          ssq[ni] = fmaf(v, v, ssq[ni]);
        }
      }
    }
  }
#pragma unroll
  for (int ni = 0; ni < 4; ++ni) {
    float s = ssum[ni], q = ssq[ni];
    s += __shfl_xor(s, 16); s += __shfl_xor(s, 32);
    q += __shfl_xor(q, 16); q += __shfl_xor(q, 32);
    if (quad == 0) {
      int col = n0 + wc + ni * 16 + l15;
      atomicAdd(&stats[col], s);
      atomicAdd(&stats[Hc + col], q);
    }
  }
}

// ---- fp32 SIMT GEMM for the VN MLP: C[M,256] = A @ W + bias. 64x64 tile. ----
__global__ __launch_bounds__(256) void k_gemm_f32(const float* __restrict__ A, const float* __restrict__ W,
                                                  const float* __restrict__ bias, float* __restrict__ C, int M) {
  __shared__ float As[64][68];
  __shared__ float Ws[64][68];
  int tid = threadIdx.x;
  int row0 = blockIdx.x * 64;
  int col0 = blockIdx.y * 64;
  int tx = tid & 15, ty = tid >> 4;
  float acc[4][4] = {{0.f}};
  for (int k0 = 0; k0 < 256; k0 += 64) {
#pragma unroll
    for (int i = 0; i < 4; ++i) {
      int lin = tid + i * 256;
      int r = lin >> 4;
      int c4 = (lin & 15) << 2;
      int gr = row0 + r;
      float4 v = make_float4(0.f, 0.f, 0.f, 0.f);
      if (gr < M) v = *(const float4*)&A[(size_t)gr * Hc + k0 + c4];
      As[r][c4] = v.x; As[r][c4 + 1] = v.y; As[r][c4 + 2] = v.z; As[r][c4 + 3] = v.w;
      float4 w = *(const float4*)&W[(size_t)(k0 + r) * Hc + col0 + c4];
      Ws[r][c4] = w.x; Ws[r][c4 + 1] = w.y; Ws[r][c4 + 2] = w.z; Ws[r][c4 + 3] = w.w;
    }
    __syncthreads();
#pragma unroll
    for (int k = 0; k < 64; ++k) {
      float a[4], w[4];
#pragma unroll
      for (int i = 0; i < 4; ++i) a[i] = As[ty * 4 + i][k];
#pragma unroll
      for (int j = 0; j < 4; ++j) w[j] = Ws[k][tx * 4 + j];
#pragma unroll
      for (int i = 0; i < 4; ++i)
#pragma unroll
        for (int j = 0; j < 4; ++j) acc[i][j] = fmaf(a[i], w[j], acc[i][j]);
    }
    __syncthreads();
  }
#pragma unroll
  for (int i = 0; i < 4; ++i) {
    int gr = row0 + ty * 4 + i;
    if (gr >= M) break;
#pragma unroll
    for (int j = 0; j < 4; ++j) {
      int gc = col0 + tx * 4 + j;
      C[(size_t)gr * Hc + gc] = acc[i][j] + bias[gc];
    }
  }
}

extern "C" void kernel_launch(void* const* d_in, const int* in_sizes, int n_in,
                              void* d_out, int out_size, void* d_ws, size_t ws_size,
                              hipStream_t stream) {
  const int* x = (const int*)d_in[0];
  const int* ei = (const int*)d_in[1];
  const int* ea = (const int*)d_in[2];
  const int* batch = (const int*)d_in[3];
  const float* aemb = (const float*)d_in[4];
  const float* bemb = (const float*)d_in[5];
  const float* vnw = (const float*)d_in[6];
  const float* conv_w = (const float*)d_in[7];
  const float* conv_b = (const float*)d_in[8];
  const float* ngamma = (const float*)d_in[9];
  const float* nbeta = (const float*)d_in[10];
  const float* vn_w = (const float*)d_in[11];
  const float* vn_b = (const float*)d_in[12];
  const float* vn_g = (const float*)d_in[13];
  const float* vn_be = (const float*)d_in[14];
  float* out = (float*)d_out;

  const size_t NODE = (size_t)Ncnt * Hc;
  const size_t GH = (size_t)Gcnt * Hc;

  size_t off = 0;
  char* base = (char*)d_ws;
  auto take = [&](size_t bytes) { size_t o = off; off += (bytes + 15) & ~(size_t)15; return o; };
  float* vn = (float*)(base + take(GH * 4));
  float* vnt = (float*)(base + take(GH * 4));
  float* vnu = (float*)(base + take(GH * 4));
  float* vnv = (float*)(base + take(GH * 4));
  float* statsN = (float*)(base + take(2 * Hc * 4));
  float* statsV = (float*)(base + take(2 * Hc * 4));
  int* rowptr = (int*)(base + take((size_t)(Ncnt + 1) * 4));
  int* cursor = (int*)(base + take((size_t)Ncnt * 4));
  int* eidx = (int*)(base + take((size_t)Ecnt * 4));
  bf16* P = (bf16*)(base + take(NODE * 2));
  bf16* T = (bf16*)(base + take(NODE * 2));
  bf16* WhiC = (bf16*)(base + take((size_t)Lcnt * 65536 * 2));
  bf16* WloC = (bf16*)(base + take((size_t)Lcnt * 65536 * 2));
  const size_t NEED = off;
  if (ws_size < NEED) {
    k_zero<<<(int)((GH + 255) / 256), 256, 0, stream>>>(out, (int)GH);
    k_diag<<<1, 1, 0, stream>>>(out, 100000.f + (float)(ws_size / (1024.0 * 1024.0)));
    return;
  }

  const int eBlk = (Ecnt + 255) / 256;
  const int nWaveBlk = (Ncnt + 3) / 4;
  const int segBlk = (Ncnt + 255) / 256;
  const int gBlk256 = (Gcnt + 255) / 256;
  const dim3 ggN((Ncnt + 127) / 128, 2);
  const dim3 gv(Gcnt / 64, 4);
  const float invN = 1.f / Ncnt;
  const float invG = 1.f / Gcnt;

  // CSR build
  k_zero_int<<<(Ncnt + 255) / 256, 256, 0, stream>>>(cursor, Ncnt);
  k_count<<<eBlk, 256, 0, stream>>>(ei, cursor);
  k_scan<<<1, 1024, 0, stream>>>(cursor, rowptr, cursor);
  k_scatter<<<eBlk, 256, 0, stream>>>(ei, cursor, eidx);

  // conv weight prep (hi/lo, transposed)
  k_prep_w<<<(Lcnt * 65536 + 255) / 256, 256, 0, stream>>>(conv_w, WhiC, WloC, Lcnt);

  // Encoders + conv0 (stats fused for layer-1 BN)
  k_atom_encode<<<nWaveBlk, 256, 0, stream>>>(x, aemb, vnw, P);
  k_init_vn<<<(int)(GH / 256), 256, 0, stream>>>(vn, vnw);
  k_agg<<<nWaveBlk, 256, 0, stream>>>(P, T, rowptr, eidx, ei, ea, bemb,
                                      nullptr, nullptr, nullptr, nullptr, nullptr, 0.f);
  k_zero<<<2, 256, 0, stream>>>(statsN, 2 * Hc);
  k_gemm_mfma<<<ggN, 256, 0, stream>>>(T, WhiC, WloC, conv_b, nullptr, P, statsN, Ncnt);

  for (int l = 1; l < Lcnt; ++l) {
    int p = l - 1;
    const float* g = ngamma + (size_t)p * Hc;
    const float* b = nbeta + (size_t)p * Hc;
    // vn_t = vn + segsum(relu(bn(P)))
    k_copy<<<(int)(GH / 256), 256, 0, stream>>>(vnt, vn, (int)GH);
    k_seg_vn<<<segBlk, 256, 0, stream>>>(P, batch, vnt, statsN, g, b, invN);
    // VN MLP j=0 (fp32 SIMT)
    k_gemm_f32<<<gv, 256, 0, stream>>>(vnt, vn_w + (size_t)(2 * p) * 65536,
                                       vn_b + (size_t)(2 * p) * Hc, vnu, Gcnt);
    k_zero<<<2, 256, 0, stream>>>(statsV, 2 * Hc);
    k_bn_stats_f<<<gBlk256, 256, 0, stream>>>(vnu, statsV, Gcnt);
    k_vn_relu<<<(int)(GH / 256), 256, 0, stream>>>(vnu, vnv, statsV,
                                                   vn_g + (size_t)(2 * p) * Hc,
                                                   vn_be + (size_t)(2 * p) * Hc, invG);
    // VN MLP j=1 -> vn
    k_gemm_f32<<<gv, 256, 0, stream>>>(vnv, vn_w + (size_t)(2 * p + 1) * 65536,
                                       vn_b + (size_t)(2 * p + 1) * Hc, vnu, Gcnt);
    k_zero<<<2, 256, 0, stream>>>(statsV, 2 * Hc);
    k_bn_stats_f<<<gBlk256, 256, 0, stream>>>(vnu, statsV, Gcnt);
    k_vn_relu<<<(int)(GH / 256), 256, 0, stream>>>(vnu, vn, statsV,
                                                   vn_g + (size_t)(2 * p + 1) * Hc,
                                                   vn_be + (size_t)(2 * p + 1) * Hc, invG);
    // T = h2 + agg(h2), h2 = relu(bn(P)) + vn[batch]
    k_agg<<<nWaveBlk, 256, 0, stream>>>(P, T, rowptr, eidx, ei, ea, bemb, vn, batch, statsN, g, b, invN);
    // P = T @ W + bias + P (stats fused for next BN)
    k_zero<<<2, 256, 0, stream>>>(statsN, 2 * Hc);
    k_gemm_mfma<<<ggN, 256, 0, stream>>>(T, WhiC + (size_t)l * 65536, WloC + (size_t)l * 65536,
                                         conv_b + (size_t)l * Hc, P, P, statsN, Ncnt);
  }

  // Final BN + global add pool
  k_zero<<<(int)((GH + 255) / 256), 256, 0, stream>>>(out, (int)GH);
  k_bn_pool<<<segBlk, 256, 0, stream>>>(P, batch, out, statsN,
                                        ngamma + (size_t)(Lcnt - 1) * Hc, nbeta + (size_t)(Lcnt - 1) * Hc,
                                        invN);
}